// Round 10
// baseline (152.197 us; speedup 1.0000x reference)
//
#include <hip/hip_runtime.h>
#include <hip/hip_bf16.h>

#define NB 32
#define NN 2048
#define DD 64
#define NCH 32
#define LOG2E 1.44269504088896340736f
#define SQC 0.4246613965f  // sqrt(0.125 * LOG2E)

typedef __attribute__((ext_vector_type(8))) short short8;
typedef __attribute__((ext_vector_type(4))) short short4v;
typedef __attribute__((ext_vector_type(4))) float f32x4;

#define MFMA32K(A, B, C) \
  __builtin_amdgcn_mfma_f32_16x16x32_bf16((A), (B), (C), 0, 0, 0)
#define MFMA16(A, B, C) \
  __builtin_amdgcn_mfma_f32_16x16x16bf16_1k((A), (B), (C), 0, 0, 0)

#define GLOAD_LDS16(gp, lp)                                                   \
  __builtin_amdgcn_global_load_lds(                                          \
      (const __attribute__((address_space(1))) void*)(gp),                   \
      (__attribute__((address_space(3))) void*)(lp), 16, 0, 0)

__device__ __forceinline__ short f2bf(float x) {
  __bf16 h = (__bf16)x;
  return __builtin_bit_cast(short, h);
}

__device__ __forceinline__ float fast_exp2(float x) {
#if __has_builtin(__builtin_amdgcn_exp2f)
  return __builtin_amdgcn_exp2f(x);
#else
  return exp2f(x);
#endif
}

// round-to-nearest bf16 pack of two positive floats: lo -> low short
__device__ __forceinline__ unsigned pack_bf16_rnd(float lo, float hi) {
  unsigned ulo = __builtin_bit_cast(unsigned, lo) + 0x8000u;
  unsigned uhi = __builtin_bit_cast(unsigned, hi) + 0x8000u;
  return __builtin_amdgcn_perm(uhi, ulo, 0x07060302u);
}

// ---------- prep: fragment-major bf16 image; K-units pre-scaled by SQC.
__global__ __launch_bounds__(256) void prep_img(const float* __restrict__ x,
                                                short* __restrict__ img) {
  __shared__ float t[64 * 68];
  const int tid = threadIdx.x;
  const int c = blockIdx.x;
  const int b = blockIdx.y;
  const int r = tid >> 2;
  const int cg = tid & 3;

  const float* src = x + ((size_t)b * NN + c * 64 + r) * DD + cg * 16;
#pragma unroll
  for (int h = 0; h < 4; ++h)
    *(float4*)&t[r * 68 + cg * 16 + h * 4] = ((const float4*)src)[h];
  __syncthreads();

  short* imgc = img + (size_t)(b * NCH + c) * 16 * 512;

  // K units (scaled by SQC)
#pragma unroll
  for (int i = 0; i < 2; ++i) {
    const int kc = tid + i * 256;
    const int u = kc >> 6, l = kc & 63;
    const int nt = u >> 1, ks = u & 1;
    const float* tr = &t[(nt * 16 + (l & 15)) * 68 + ks * 32 + (l >> 4) * 8];
    short8 v;
#pragma unroll
    for (int j = 0; j < 8; ++j) v[j] = f2bf(tr[j] * SQC);
    *(short8*)&imgc[(size_t)u * 512 + l * 8] = v;
  }
  // V units (unscaled, transposed gather)
#pragma unroll
  for (int i = 0; i < 2; ++i) {
    const int vc = tid + i * 256;
    const int u = vc >> 6, l = vc & 63;
    const int dt = u >> 1, ntp = u & 1;
    const int d = dt * 16 + (l & 15);
    const int k0 = ntp * 32 + ((l >> 4) << 2);
    short8 o;
#pragma unroll
    for (int h = 0; h < 2; ++h)
#pragma unroll
      for (int r2 = 0; r2 < 4; ++r2)
        o[h * 4 + r2] = f2bf(t[(k0 + h * 16 + r2) * 68 + d]);
    *(short8*)&imgc[(size_t)(8 + u) * 512 + l * 8] = o;
  }
}

// ---------- prep 2: adj int32 -> bitmask
__global__ __launch_bounds__(256) void prep_adj(const int* __restrict__ adj,
                                                unsigned long long* __restrict__ bits) {
  const int i = blockIdx.x * 256 + threadIdx.x;
  unsigned long long m = __ballot(adj[i] > 0);
  if ((threadIdx.x & 63) == 0) bits[i >> 6] = m;
}

// ---------- main: 2 waves x 32 q-rows = 64 q-rows/block; 1024 blocks
// XCD-swizzled (4 batches/XCD, img L2-resident). Software-pipelined chunk
// body: QK(nt+1) MFMAs issued before softmax(nt) VALU and PV(nt) MFMA16s,
// so the MFMA pipe, VALU, and LDS stay co-busy within a single wave.
__global__ __launch_bounds__(128, 2) void gat_flash9(
    const short* __restrict__ img, const unsigned long long* __restrict__ adjb,
    float* __restrict__ out) {
  __shared__ short sI[2][8192];  // double-buffered chunk image (16 KB each)

  const int beta = blockIdx.x;
  const int xcd = beta & 7;
  const int idx = beta >> 3;     // 0..127 within XCD
  const int bb = idx >> 5;       // batch within XCD (0..3)
  const int xq = idx & 31;       // 64-row q-tile
  const int b = xcd * 4 + bb;

  const int tid = threadIdx.x;
  const int w = tid >> 6;        // 0..1
  const int l = tid & 63;
  const int lane16 = l & 15;
  const int quad = l >> 4;
  const int qbase = xq * 64 + w * 32;
  const int coff = idx & 31;     // staggered chunk start (order-free softmax)

  const short* img_b = img + (size_t)b * NCH * 8192;

  // Q B-frags from the img K-units of this wave's own q-chunk (xq):
  // total scale = SQC(K) * SQC(Q) = 0.125*log2e
  short8 qf[2][2];
#pragma unroll
  for (int qt = 0; qt < 2; ++qt)
#pragma unroll
    for (int ks = 0; ks < 2; ++ks)
      qf[qt][ks] = *(const short8*)&img_b[((size_t)xq * 16 +
                                          (w * 2 + qt) * 2 + ks) * 512 + l * 8];

  f32x4 acc[2][4];  // [qt][dt]: row=d=quad*4+reg, col=q=lane16
  f32x4 acl[2];
#pragma unroll
  for (int qt = 0; qt < 2; ++qt) {
    acl[qt] = {0.f, 0.f, 0.f, 0.f};
#pragma unroll
    for (int dt = 0; dt < 4; ++dt) acc[qt][dt] = {0.f, 0.f, 0.f, 0.f};
  }
  short4v ones;
  ones[0] = 0x3F80; ones[1] = 0x3F80; ones[2] = 0x3F80; ones[3] = 0x3F80;
  const f32x4 zero = {0.f, 0.f, 0.f, 0.f};

  const unsigned long long* ar0 = adjb + (size_t)(qbase + lane16) * NCH;
  const unsigned long long* ar1 = adjb + (size_t)(qbase + 16 + lane16) * NCH;

  // stage first chunk (wave w handles units w, w+2, ..., w+14)
  {
    const short* p = img_b + (size_t)coff * 8192;
#pragma unroll
    for (int i = 0; i < 8; ++i) {
      const int u = i * 2 + w;
      GLOAD_LDS16(p + (size_t)u * 512 + l * 8, &sI[0][u * 512]);
    }
  }
  __syncthreads();

  for (int ci = 0; ci < NCH; ++ci) {
    const int c = (ci + coff) & 31;
    const int cur = ci & 1;
    if (ci < NCH - 1) {
      const int cn = (ci + 1 + coff) & 31;
      const short* p = img_b + (size_t)cn * 8192;
#pragma unroll
      for (int i = 0; i < 8; ++i) {
        const int u = i * 2 + w;
        GLOAD_LDS16(p + (size_t)u * 512 + l * 8, &sI[cur ^ 1][u * 512]);
      }
    }

    const unsigned long long a0 = ar0[c] >> (quad * 4);
    const unsigned long long a1 = ar1[c] >> (quad * 4);
    const unsigned m0[2] = {(unsigned)a0, (unsigned)(a0 >> 32)};
    const unsigned m1[2] = {(unsigned)a1, (unsigned)(a1 >> 32)};

    const short* sKc = sI[cur];
    const short* sVc = sI[cur] + 4096;

    f32x4 sS[2][2];  // [pingpong][qt]
    // QK tile 0
    {
      short8 k0 = *(const short8*)&sKc[0 * 512 + l * 8];
      short8 k1 = *(const short8*)&sKc[1 * 512 + l * 8];
      sS[0][0] = MFMA32K(k0, qf[0][0], zero);
      sS[0][0] = MFMA32K(k1, qf[0][1], sS[0][0]);
      sS[0][1] = MFMA32K(k0, qf[1][0], zero);
      sS[0][1] = MFMA32K(k1, qf[1][1], sS[0][1]);
    }

    short8 vv[4];
#pragma unroll
    for (int nt = 0; nt < 4; ++nt) {
      const int pp = nt & 1;
      // QK tile nt+1 (independent — overlaps softmax(nt) below)
      if (nt < 3) {
        short8 k0 = *(const short8*)&sKc[((nt + 1) * 2) * 512 + l * 8];
        short8 k1 = *(const short8*)&sKc[((nt + 1) * 2 + 1) * 512 + l * 8];
        sS[pp ^ 1][0] = MFMA32K(k0, qf[0][0], zero);
        sS[pp ^ 1][0] = MFMA32K(k1, qf[0][1], sS[pp ^ 1][0]);
        sS[pp ^ 1][1] = MFMA32K(k0, qf[1][0], zero);
        sS[pp ^ 1][1] = MFMA32K(k1, qf[1][1], sS[pp ^ 1][1]);
      }
      // V b128s for this ntp (even nt), halves used at nt and nt+1
      if (pp == 0) {
#pragma unroll
        for (int dt = 0; dt < 4; ++dt)
          vv[dt] = *(const short8*)&sVc[(dt * 2 + (nt >> 1)) * 512 + l * 8];
      }
      // softmax of sS[pp]
      const unsigned w0 = m0[nt >> 1], w1 = m1[nt >> 1];
      const int sh = pp * 16;
      float p0[4], p1[4];
#pragma unroll
      for (int r = 0; r < 4; ++r) {
        float e0 = fast_exp2(sS[pp][0][r]);
        float e1 = fast_exp2(sS[pp][1][r]);
        p0[r] = ((w0 >> (sh + r)) & 1u) ? e0 : 0.f;
        p1[r] = ((w1 >> (sh + r)) & 1u) ? e1 : 0.f;
      }
      uint2 u0, u1;
      u0.x = pack_bf16_rnd(p0[0], p0[1]);
      u0.y = pack_bf16_rnd(p0[2], p0[3]);
      u1.x = pack_bf16_rnd(p1[0], p1[1]);
      u1.y = pack_bf16_rnd(p1[2], p1[3]);
      short4v pf0 = __builtin_bit_cast(short4v, u0);
      short4v pf1 = __builtin_bit_cast(short4v, u1);
      acl[0] = MFMA16(ones, pf0, acl[0]);
      acl[1] = MFMA16(ones, pf1, acl[1]);
      // PV with the matching half of vv
#pragma unroll
      for (int dt = 0; dt < 4; ++dt) {
        short4v vh = (pp == 0)
                         ? __builtin_shufflevector(vv[dt], vv[dt], 0, 1, 2, 3)
                         : __builtin_shufflevector(vv[dt], vv[dt], 4, 5, 6, 7);
        acc[0][dt] = MFMA16(vh, pf0, acc[0][dt]);
        acc[1][dt] = MFMA16(vh, pf1, acc[1][dt]);
      }
    }
    __syncthreads();
  }

  // ---- epilogue: lane holds l[q=lane16] in acl[qt][0] ----
#pragma unroll
  for (int qt = 0; qt < 2; ++qt) {
    const float inv = 1.0f / acl[qt][0];
    float* op =
        out + ((size_t)b * NN + qbase + qt * 16 + lane16) * DD + quad * 4;
#pragma unroll
    for (int dt = 0; dt < 4; ++dt) {
      float4 o;
      o.x = acc[qt][dt][0] * inv;
      o.y = acc[qt][dt][1] * inv;
      o.z = acc[qt][dt][2] * inv;
      o.w = acc[qt][dt][3] * inv;
      *(float4*)(op + dt * 16) = o;
    }
  }
}

extern "C" void kernel_launch(void* const* d_in, const int* in_sizes, int n_in,
                              void* d_out, int out_size, void* d_ws,
                              size_t ws_size, hipStream_t stream) {
  const float* x = (const float*)d_in[0];
  const int* adj = (const int*)d_in[1];
  float* out = (float*)d_out;

  short* img = (short*)d_ws;  // 16 MB fragment-major image
  unsigned long long* adjb =
      (unsigned long long*)(img + (size_t)NB * NCH * 16 * 512);  // 512 KB

  prep_img<<<dim3(NCH, NB), 256, 0, stream>>>(x, img);
  prep_adj<<<(NN * NN) / 256, 256, 0, stream>>>(adj, adjb);
  gat_flash9<<<1024, 128, 0, stream>>>(img, adjb, out);
}

// Round 11
// 150.688 us; speedup vs baseline: 1.0100x; 1.0100x over previous
//
#include <hip/hip_runtime.h>
#include <hip/hip_bf16.h>

#define NB 32
#define NN 2048
#define DD 64
#define NCH 32
#define LOG2E 1.44269504088896340736f
#define SQC 0.4246613965f  // sqrt(0.125 * LOG2E)

typedef __attribute__((ext_vector_type(8))) short short8;
typedef __attribute__((ext_vector_type(4))) short short4v;
typedef __attribute__((ext_vector_type(4))) float f32x4;

#define MFMA32K(A, B, C) \
  __builtin_amdgcn_mfma_f32_16x16x32_bf16((A), (B), (C), 0, 0, 0)

__device__ __forceinline__ short f2bf(float x) {
  __bf16 h = (__bf16)x;
  return __builtin_bit_cast(short, h);
}

__device__ __forceinline__ float fast_exp2(float x) {
#if __has_builtin(__builtin_amdgcn_exp2f)
  return __builtin_amdgcn_exp2f(x);
#else
  return exp2f(x);
#endif
}

// round-to-nearest bf16 pack of two positive floats: lo -> low short
__device__ __forceinline__ unsigned pack_bf16_rnd(float lo, float hi) {
  unsigned ulo = __builtin_bit_cast(unsigned, lo) + 0x8000u;
  unsigned uhi = __builtin_bit_cast(unsigned, hi) + 0x8000u;
  return __builtin_amdgcn_perm(uhi, ulo, 0x07060302u);
}

// ---------- prep: fragment-major bf16 image.
// K units u=0..7 (nt=u>>1, ks=u&1): lane l -> K[c*64+nt*16+(l&15)][ks*32+(l>>4)*8+j] (SQC-scaled)
// V units u=8..15 (dt=(u-8)>>1, win=(u-8)&1): lane l -> x32 A-frag
//   V^T[dt*16+(l&15)][c*64 + win*32 + (l>>4)*8 + j]
__global__ __launch_bounds__(256) void prep_img(const float* __restrict__ x,
                                                short* __restrict__ img) {
  __shared__ float t[64 * 68];
  const int tid = threadIdx.x;
  const int c = blockIdx.x;
  const int b = blockIdx.y;
  const int r = tid >> 2;
  const int cg = tid & 3;

  const float* src = x + ((size_t)b * NN + c * 64 + r) * DD + cg * 16;
#pragma unroll
  for (int h = 0; h < 4; ++h)
    *(float4*)&t[r * 68 + cg * 16 + h * 4] = ((const float4*)src)[h];
  __syncthreads();

  short* imgc = img + (size_t)(b * NCH + c) * 16 * 512;

  // K units (scaled by SQC; Q frags reuse these units -> total scale SQC^2)
#pragma unroll
  for (int i = 0; i < 2; ++i) {
    const int kc = tid + i * 256;
    const int u = kc >> 6, l = kc & 63;
    const int nt = u >> 1, ks = u & 1;
    const float* tr = &t[(nt * 16 + (l & 15)) * 68 + ks * 32 + (l >> 4) * 8];
    short8 v;
#pragma unroll
    for (int j = 0; j < 8; ++j) v[j] = f2bf(tr[j] * SQC);
    *(short8*)&imgc[(size_t)u * 512 + l * 8] = v;
  }
  // V units in x32 A-frag order (d = m-row, 8 consecutive keys per lane)
#pragma unroll
  for (int i = 0; i < 2; ++i) {
    const int vc = tid + i * 256;
    const int u = vc >> 6, l = vc & 63;
    const int dt = u >> 1, win = u & 1;
    const int d = dt * 16 + (l & 15);
    const int key0 = win * 32 + (l >> 4) * 8;
    short8 o;
#pragma unroll
    for (int j = 0; j < 8; ++j) o[j] = f2bf(t[(key0 + j) * 68 + d]);
    *(short8*)&imgc[(size_t)(8 + u) * 512 + l * 8] = o;
  }
}

// ---------- prep 2: adj int32 -> bitmask
__global__ __launch_bounds__(256) void prep_adj(const int* __restrict__ adj,
                                                unsigned long long* __restrict__ bits) {
  const int i = blockIdx.x * 256 + threadIdx.x;
  unsigned long long m = __ballot(adj[i] > 0);
  if ((threadIdx.x & 63) == 0) bits[i >> 6] = m;
}

// ---------- main: 4 waves x 32 q-rows = 128 q-rows/block; 512 blocks
// XCD-swizzled. NO __syncthreads, NO LDS staging: K/V/Q fragments load
// directly from the L2-resident fragment-major img (all waves of a block
// read identical addresses -> L1 hits). All MFMAs are native 16x16x32.
// P^T goes C-layout -> B-frag layout through a 4 KB per-wave LDS scratch
// laid out in exact read order (reads = lane*16B, conflict-free).
__global__ __launch_bounds__(256, 2) void gat_flash10(
    const short* __restrict__ img, const unsigned long long* __restrict__ adjb,
    float* __restrict__ out) {
  __shared__ short sP[4 * 2048];  // 4 waves x 4 units x 512 shorts = 16 KB

  const int beta = blockIdx.x;
  const int xcd = beta & 7;
  const int idx = beta >> 3;   // 0..63 within XCD
  const int bb = idx >> 4;     // batch within XCD (0..3)
  const int xq = idx & 15;     // 128-row q-tile
  const int b = xcd * 4 + bb;

  const int tid = threadIdx.x;
  const int w = tid >> 6;
  const int l = tid & 63;
  const int lane16 = l & 15;
  const int quad = l >> 4;
  const int qbase = xq * 128 + w * 32;
  const int coff = (idx * 11) & 31;  // stagger chunk order (sums commute)

  const short* img_b = img + (size_t)b * NCH * 8192;
  short* sPw = sP + w * 2048;

  // Q B-frags from img K-units of this wave's own q-chunk
  const int qc = xq * 2 + (w >> 1);
  short8 qf[2][2];
#pragma unroll
  for (int qt = 0; qt < 2; ++qt)
#pragma unroll
    for (int ks = 0; ks < 2; ++ks)
      qf[qt][ks] = *(const short8*)&img_b[((size_t)qc * 16 +
                                          ((w & 1) * 2 + qt) * 2 + ks) * 512 +
                                          l * 8];

  f32x4 acc[2][4];  // [qt][dt]: row=d=quad*4+reg, col=q=lane16
#pragma unroll
  for (int qt = 0; qt < 2; ++qt)
#pragma unroll
    for (int dt = 0; dt < 4; ++dt) acc[qt][dt] = {0.f, 0.f, 0.f, 0.f};
  float lpart[2] = {0.f, 0.f};
  const f32x4 zero = {0.f, 0.f, 0.f, 0.f};

  const unsigned long long* ar0 = adjb + (size_t)(qbase + lane16) * NCH;
  const unsigned long long* ar1 = adjb + (size_t)(qbase + 16 + lane16) * NCH;

  for (int ci = 0; ci < NCH; ++ci) {
    const int cc = (ci + coff) & 31;
    const short* gc = img_b + (size_t)cc * 8192;

    // fragment loads (coalesced 1 KB each; L1-hot across the block's waves)
    short8 kf[8], vf[8];
#pragma unroll
    for (int u = 0; u < 8; ++u) kf[u] = *(const short8*)&gc[u * 512 + l * 8];
#pragma unroll
    for (int u = 0; u < 8; ++u)
      vf[u] = *(const short8*)&gc[(8 + u) * 512 + l * 8];

    const unsigned long long a0 = ar0[cc] >> (quad * 4);
    const unsigned long long a1 = ar1[cc] >> (quad * 4);
    const unsigned m0[2] = {(unsigned)a0, (unsigned)(a0 >> 32)};
    const unsigned m1[2] = {(unsigned)a1, (unsigned)(a1 >> 32)};

    // ---- QK + softmax; P^T written to scratch in B-frag unit order ----
#pragma unroll
    for (int nt = 0; nt < 4; ++nt) {
      f32x4 s0 = MFMA32K(kf[nt * 2], qf[0][0], zero);
      s0 = MFMA32K(kf[nt * 2 + 1], qf[0][1], s0);
      f32x4 s1 = MFMA32K(kf[nt * 2], qf[1][0], zero);
      s1 = MFMA32K(kf[nt * 2 + 1], qf[1][1], s1);

      const unsigned w0 = m0[nt >> 1], w1 = m1[nt >> 1];
      const int sh = (nt & 1) * 16;
      float p0[4], p1[4];
#pragma unroll
      for (int r = 0; r < 4; ++r) {
        float e0 = fast_exp2(s0[r]);
        float e1 = fast_exp2(s1[r]);
        p0[r] = ((w0 >> (sh + r)) & 1u) ? e0 : 0.f;
        p1[r] = ((w1 >> (sh + r)) & 1u) ? e1 : 0.f;
        lpart[0] += p0[r];
        lpart[1] += p1[r];
      }
      uint2 u0, u1;
      u0.x = pack_bf16_rnd(p0[0], p0[1]);
      u0.y = pack_bf16_rnd(p0[2], p0[3]);
      u1.x = pack_bf16_rnd(p1[0], p1[1]);
      u1.y = pack_bf16_rnd(p1[2], p1[3]);
      // dest: unit (win*2+qt), lane lq = ((nt&1)*2 + quad>>1)*16 + lane16,
      // j-offset (quad&1)*4  -> write banks 2-way (free), reads lane*16.
      const int win = nt >> 1;
      const int lq = ((nt & 1) * 2 + (quad >> 1)) * 16 + lane16;
      const int off = lq * 8 + (quad & 1) * 4;
      *(short4v*)&sPw[(win * 2 + 0) * 512 + off] = __builtin_bit_cast(short4v, u0);
      *(short4v*)&sPw[(win * 2 + 1) * 512 + off] = __builtin_bit_cast(short4v, u1);
    }

    // ---- PV: all native x32; A = V-frag (global), B = P-frag (scratch) ----
#pragma unroll
    for (int win = 0; win < 2; ++win)
#pragma unroll
      for (int qt = 0; qt < 2; ++qt) {
        short8 pfrag = *(const short8*)&sPw[(win * 2 + qt) * 512 + l * 8];
#pragma unroll
        for (int dt = 0; dt < 4; ++dt)
          acc[qt][dt] = MFMA32K(vf[dt * 2 + win], pfrag, acc[qt][dt]);
      }
    // per-wave scratch: in-order LDS per wave makes next chunk's writes safe
  }

  // ---- l reduce across quads (keys partitioned by quad), then store ----
#pragma unroll
  for (int qt = 0; qt < 2; ++qt) {
    float lq = lpart[qt];
    lq += __shfl_xor(lq, 16, 64);
    lq += __shfl_xor(lq, 32, 64);
    const float inv = 1.0f / lq;
    float* op =
        out + ((size_t)b * NN + qbase + qt * 16 + lane16) * DD + quad * 4;
#pragma unroll
    for (int dt = 0; dt < 4; ++dt) {
      float4 o;
      o.x = acc[qt][dt][0] * inv;
      o.y = acc[qt][dt][1] * inv;
      o.z = acc[qt][dt][2] * inv;
      o.w = acc[qt][dt][3] * inv;
      *(float4*)(op + dt * 16) = o;
    }
  }
}

extern "C" void kernel_launch(void* const* d_in, const int* in_sizes, int n_in,
                              void* d_out, int out_size, void* d_ws,
                              size_t ws_size, hipStream_t stream) {
  const float* x = (const float*)d_in[0];
  const int* adj = (const int*)d_in[1];
  float* out = (float*)d_out;

  short* img = (short*)d_ws;  // 16 MB fragment-major image
  unsigned long long* adjb =
      (unsigned long long*)(img + (size_t)NB * NCH * 16 * 512);  // 512 KB

  prep_img<<<dim3(NCH, NB), 256, 0, stream>>>(x, img);
  prep_adj<<<(NN * NN) / 256, 256, 0, stream>>>(adj, adjb);
  gat_flash10<<<512, 256, 0, stream>>>(img, adjb, out);
}